// Round 1
// baseline (945.750 us; speedup 1.0000x reference)
//
#include <hip/hip_runtime.h>
#include <hip/hip_bf16.h>
#include <stdint.h>

typedef __attribute__((ext_vector_type(8))) short s16x8;
typedef __attribute__((ext_vector_type(4))) float f32x4;

#define D_DIM 2048
#define V_DIM 32768
#define M_DIM 4096
#define N_SEQ 2048
#define K_TOP 64
#define BM 128
#define BNV 128
#define BK 32
#define NSLOT 512   // 256 v-tiles * 2 wc halves

// ---------- helpers ----------
static __device__ __forceinline__ float bf2f(unsigned short u) {
  union { unsigned int i; float f; } v; v.i = ((unsigned int)u) << 16; return v.f;
}

static __device__ __forceinline__ unsigned int pack2_bf16(float lo, float hi) {
  unsigned int ul = __float_as_uint(lo), uh = __float_as_uint(hi);
  ul = (ul + 0x7FFFu + ((ul >> 16) & 1u)) >> 16;        // RNE
  uh = (uh + 0x7FFFu + ((uh >> 16) & 1u)) >> 16;
  return ul | (uh << 16);
}

typedef __attribute__((address_space(3))) unsigned int lds_u32_t;
typedef const __attribute__((address_space(1))) unsigned int glb_u32_t;
static __device__ __forceinline__ void gload16(const void* g, void* l) {
  __builtin_amdgcn_global_load_lds((glb_u32_t*)g, (lds_u32_t*)l, 16, 0, 0);
}

// ---------- cast f32 -> bf16, 8 elems/thread ----------
__global__ void cast_bf16_kernel(const float4* __restrict__ in,
                                 uint4* __restrict__ out, int n8) {
  int i = blockIdx.x * blockDim.x + threadIdx.x;
  int stride = gridDim.x * blockDim.x;
  for (; i < n8; i += stride) {
    float4 a = in[2 * i], b = in[2 * i + 1];
    uint4 r;
    r.x = pack2_bf16(a.x, a.y);
    r.y = pack2_bf16(a.z, a.w);
    r.z = pack2_bf16(b.x, b.y);
    r.w = pack2_bf16(b.z, b.w);
    out[i] = r;
  }
}

// ---------- main GEMM + online (max,sumexp) partials ----------
__global__ __launch_bounds__(256) void gemm_lse_kernel(
    const unsigned short* __restrict__ xbf,   // [M_DIM][D_DIM]
    const unsigned short* __restrict__ wbf,   // [V_DIM][D_DIM]
    float* __restrict__ pMax,                 // [M_DIM][NSLOT]
    float* __restrict__ pSum) {
  __shared__ __align__(16) unsigned short As[BM * BK];  // 8 KB
  __shared__ __align__(16) unsigned short Bs[BNV * BK]; // 8 KB

  const int bid = blockIdx.x;
  const int vt = bid & 255;       // 256 v-tiles
  const int mt = bid >> 8;        // 32 m-tiles
  const int tid = threadIdx.x;
  const int lane = tid & 63;
  const int w = tid >> 6;         // 4 waves
  const int wr = w >> 1, wc = w & 1;

  const long long abase = (long long)mt * BM * D_DIM;
  const long long bbase = (long long)vt * BNV * D_DIM;

  // staging map: byte off in 8KB tile = w*2048 + issue*1024 + lane*16
  const int r0 = w * 32 + (lane >> 2);   // row for issue 0 (issue 1: +16)
  const int c0 = (lane & 3) * 8;         // bf16 col

  f32x4 acc[4][4];
  for (int i = 0; i < 4; i++)
    for (int j = 0; j < 4; j++) acc[i][j] = (f32x4){0.f, 0.f, 0.f, 0.f};

  const int fr = lane & 15;
  const int kq = (lane >> 4) * 8;

  for (int kt = 0; kt < D_DIM; kt += BK) {
    const unsigned short* ga0 = xbf + abase + (long long)r0 * D_DIM + kt + c0;
    const unsigned short* gb0 = wbf + bbase + (long long)r0 * D_DIM + kt + c0;
    gload16(ga0, &As[r0 * BK + c0]);
    gload16(ga0 + 16 * D_DIM, &As[(r0 + 16) * BK + c0]);
    gload16(gb0, &Bs[r0 * BK + c0]);
    gload16(gb0 + 16 * D_DIM, &Bs[(r0 + 16) * BK + c0]);
    __syncthreads();   // drains vmcnt + barrier

    s16x8 af[4], bfr[4];
#pragma unroll
    for (int mi = 0; mi < 4; mi++)
      af[mi] = *(const s16x8*)&As[(wr * 64 + mi * 16 + fr) * BK + kq];
#pragma unroll
    for (int ni = 0; ni < 4; ni++)
      bfr[ni] = *(const s16x8*)&Bs[(wc * 64 + ni * 16 + fr) * BK + kq];
#pragma unroll
    for (int mi = 0; mi < 4; mi++)
#pragma unroll
      for (int ni = 0; ni < 4; ni++)
        acc[mi][ni] = __builtin_amdgcn_mfma_f32_16x16x32_bf16(
            af[mi], bfr[ni], acc[mi][ni], 0, 0, 0);
    __syncthreads();
  }

  // epilogue: per-row (max, sumexp) over this block's 64-col wave slice
  const int fq = lane >> 4;
  const int slot = vt * 2 + wc;
#pragma unroll
  for (int mi = 0; mi < 4; mi++) {
#pragma unroll
    for (int j = 0; j < 4; j++) {
      const int row = mt * BM + wr * 64 + mi * 16 + fq * 4 + j;
      float v0 = acc[mi][0][j], v1 = acc[mi][1][j];
      float v2 = acc[mi][2][j], v3 = acc[mi][3][j];
      float mx = fmaxf(fmaxf(v0, v1), fmaxf(v2, v3));
      for (int s = 1; s < 16; s <<= 1) mx = fmaxf(mx, __shfl_xor(mx, s));
      float sm = __expf(v0 - mx) + __expf(v1 - mx) +
                 __expf(v2 - mx) + __expf(v3 - mx);
      for (int s = 1; s < 16; s <<= 1) sm += __shfl_xor(sm, s);
      if ((lane & 15) == 0) {
        pMax[row * NSLOT + slot] = mx;
        pSum[row * NSLOT + slot] = sm;
      }
    }
  }
}

// ---------- gather: 64 target logits + gold logit per row ----------
__global__ __launch_bounds__(256) void gather_kernel(
    const unsigned short* __restrict__ xbf,
    const unsigned short* __restrict__ wbf,
    const int* __restrict__ tgt_ids,      // [M_DIM][K_TOP]
    const int* __restrict__ true_labels,  // [M_DIM]
    float* __restrict__ gout) {           // [M_DIM][K_TOP+1]
  const int m = blockIdx.x;
  const int tid = threadIdx.x, lane = tid & 63, w = tid >> 6;
  __shared__ __align__(16) unsigned short xs[D_DIM];
  *(s16x8*)&xs[tid * 8] = *(const s16x8*)&xbf[(long long)m * D_DIM + tid * 8];
  __syncthreads();
  const int n = m & (N_SEQ - 1);
  for (int k = w; k < K_TOP + 1; k += 4) {
    int id;
    if (k < K_TOP) id = tgt_ids[m * K_TOP + k];
    else id = (n < N_SEQ - 1) ? true_labels[m + 1] : 0;
    const unsigned short* wrow = wbf + (long long)id * D_DIM;
    float accv = 0.f;
#pragma unroll
    for (int j = 0; j < 4; j++) {
      s16x8 wv = *(const s16x8*)&wrow[j * 512 + lane * 8];
      s16x8 xv = *(const s16x8*)&xs[j * 512 + lane * 8];
#pragma unroll
      for (int e = 0; e < 8; e++)
        accv += bf2f((unsigned short)wv[e]) * bf2f((unsigned short)xv[e]);
    }
    for (int s = 1; s < 64; s <<= 1) accv += __shfl_xor(accv, s);
    if (lane == 0) gout[m * (K_TOP + 1) + k] = accv;
  }
}

// ---------- final: lse merge + CE + KD, atomic into scalar ----------
__global__ __launch_bounds__(256) void reduce_kernel(
    const float* __restrict__ pMax, const float* __restrict__ pSum,
    const float* __restrict__ gout, const float* __restrict__ t_lp,
    const int* __restrict__ t_mask, float* __restrict__ out) {
  const int tid = threadIdx.x, lane = tid & 63, w = tid >> 6;
  const int m = blockIdx.x * 4 + w;

  float msl[8], ssl[8];
  float M = -1e30f;
#pragma unroll
  for (int j = 0; j < 8; j++) {
    msl[j] = pMax[m * NSLOT + lane + j * 64];
    ssl[j] = pSum[m * NSLOT + lane + j * 64];
    M = fmaxf(M, msl[j]);
  }
  for (int s = 1; s < 64; s <<= 1) M = fmaxf(M, __shfl_xor(M, s));
  float S = 0.f;
#pragma unroll
  for (int j = 0; j < 8; j++) S += ssl[j] * __expf(msl[j] - M);
  for (int s = 1; s < 64; s <<= 1) S += __shfl_xor(S, s);
  const float lse = M + logf(S);

  const int n = m & (N_SEQ - 1);
  float ce = 0.f;
  if (n < N_SEQ - 1) ce = lse - gout[m * (K_TOP + 1) + K_TOP];

  // KD: one lane per k
  const float g = gout[m * (K_TOP + 1) + lane];
  float gM = g;
  for (int s = 1; s < 64; s <<= 1) gM = fmaxf(gM, __shfl_xor(gM, s));
  float gE = __expf(g - gM);
  float gS = gE;
  for (int s = 1; s < 64; s <<= 1) gS += __shfl_xor(gS, s);
  const float lseK = gM + logf(gS);

  const float tl = t_lp[m * K_TOP + lane];
  const int mk = t_mask[m * K_TOP + lane];
  float kd = mk ? __expf(tl) * (tl - (g - lseK)) : 0.f;
  for (int s = 1; s < 64; s <<= 1) kd += __shfl_xor(kd, s);

  if (lane == 0) atomicAdd(out, 0.5f * kd + 0.5f * ce);
}

// ---------- launch ----------
extern "C" void kernel_launch(void* const* d_in, const int* in_sizes, int n_in,
                              void* d_out, int out_size, void* d_ws, size_t ws_size,
                              hipStream_t stream) {
  const float* x   = (const float*)d_in[0];   // [2,2048,2048]
  const float* Wm  = (const float*)d_in[1];   // [32768,2048]
  const int* tids  = (const int*)d_in[2];     // [2,2048,64]
  const float* tlp = (const float*)d_in[3];   // [2,2048,64]
  const int* tmask = (const int*)d_in[4];     // [2,2048,64]
  const int* tlab  = (const int*)d_in[5];     // [2,2048]
  float* out = (float*)d_out;

  char* ws = (char*)d_ws;
  unsigned short* wbf = (unsigned short*)ws;                       // 128 MB
  unsigned short* xbf = (unsigned short*)(ws + (size_t)V_DIM * D_DIM * 2);  // 16 MB
  float* pMax = (float*)(ws + (size_t)V_DIM * D_DIM * 2 + (size_t)M_DIM * D_DIM * 2);
  float* pSum = pMax + (size_t)M_DIM * NSLOT;
  float* gout = pSum + (size_t)M_DIM * NSLOT;

  hipMemsetAsync(d_out, 0, sizeof(float), stream);

  cast_bf16_kernel<<<8192, 256, 0, stream>>>(
      (const float4*)Wm, (uint4*)wbf, (V_DIM * D_DIM) / 8);
  cast_bf16_kernel<<<2048, 256, 0, stream>>>(
      (const float4*)x, (uint4*)xbf, (M_DIM * D_DIM) / 8);

  gemm_lse_kernel<<<(M_DIM / BM) * (V_DIM / BNV), 256, 0, stream>>>(
      xbf, wbf, pMax, pSum);

  gather_kernel<<<M_DIM, 256, 0, stream>>>(xbf, wbf, tids, tlab, gout);

  reduce_kernel<<<M_DIM / 4, 256, 0, stream>>>(pMax, pSum, gout, tlp, tmask, out);
}

// Round 2
// 779.459 us; speedup vs baseline: 1.2133x; 1.2133x over previous
//
#include <hip/hip_runtime.h>
#include <hip/hip_bf16.h>
#include <stdint.h>

typedef __attribute__((ext_vector_type(8))) short s16x8;
typedef __attribute__((ext_vector_type(4))) float f32x4;

#define D_DIM 2048
#define V_DIM 32768
#define M_DIM 4096
#define N_SEQ 2048
#define K_TOP 64
#define NSLOT 512   // 128 v-tiles * 4 wc

// ---------- helpers ----------
static __device__ __forceinline__ float bf2f(unsigned short u) {
  union { unsigned int i; float f; } v; v.i = ((unsigned int)u) << 16; return v.f;
}
static __device__ __forceinline__ unsigned int pack2_bf16(float lo, float hi) {
  unsigned int ul = __float_as_uint(lo), uh = __float_as_uint(hi);
  ul = (ul + 0x7FFFu + ((ul >> 16) & 1u)) >> 16;        // RNE
  uh = (uh + 0x7FFFu + ((uh >> 16) & 1u)) >> 16;
  return ul | (uh << 16);
}
typedef __attribute__((address_space(3))) unsigned int lds_u32_t;
typedef const __attribute__((address_space(1))) unsigned int glb_u32_t;
static __device__ __forceinline__ void gload16(const void* g, void* l) {
  __builtin_amdgcn_global_load_lds((glb_u32_t*)g, (lds_u32_t*)l, 16, 0, 0);
}

// ---------- cast f32 -> bf16 ----------
__global__ void cast_bf16_kernel(const float4* __restrict__ in,
                                 uint4* __restrict__ out, int n8) {
  int i = blockIdx.x * blockDim.x + threadIdx.x;
  int stride = gridDim.x * blockDim.x;
  for (; i < n8; i += stride) {
    float4 a = in[2 * i], b = in[2 * i + 1];
    uint4 r;
    r.x = pack2_bf16(a.x, a.y);
    r.y = pack2_bf16(a.z, a.w);
    r.z = pack2_bf16(b.x, b.y);
    r.w = pack2_bf16(b.z, b.w);
    out[i] = r;
  }
}

// ---------- 256x256 8-phase GEMM + online (max,sumexp) partials ----------
// Tile: BM=BN=256, BK=64, 8 waves (2M x 4N), 512 thr, 128 KiB LDS dbuf.
// Half-tiles per K-tile: pos0=B[v 0:128), pos1=B[v 128:256), pos2=A[m 0:128), pos3=A[m 128:256)
// LDS swizzle: 16B-granule index ^= (row & 7); inverse pre-applied on global src.

#define BAR do { __builtin_amdgcn_s_barrier(); asm volatile("" ::: "memory"); } while (0)
#define VMC(N) asm volatile("s_waitcnt vmcnt(" #N ")" ::: "memory")
#define PRIO1 __builtin_amdgcn_s_setprio(1)
#define PRIO0 __builtin_amdgcn_s_setprio(0)

#define LDFRAG(BASE, R, G) \
  (*(const s16x8*)((BASE) + (R) * 128 + ((((G)) ^ ((R) & 7)) << 4)))
#define LDA(BASE, MI, KS) LDFRAG(BASE, (MI) * 16 + fr, (KS) * 4 + kqg)
#define LDB(BASE, NI, KS) LDFRAG(BASE, brow + (NI) * 16 + fr, (KS) * 4 + kqg)

#define STAGE(H) do { \
  int tt_ = (H) >> 2, pos_ = (H) & 3; \
  char* dst_ = ldst + ((tt_ & 1) << 16) + (pos_ << 14); \
  const unsigned short* src_ = ((pos_ & 2) ? aptr : bptr) \
      + ((pos_ & 1) ? (size_t)128 * D_DIM : (size_t)0) + (size_t)tt_ * 64; \
  gload16(src_, dst_); \
  gload16(src_ + (size_t)64 * D_DIM, dst_ + 8192); \
} while (0)

#define MFMA_Q(M0, U) do { \
  _Pragma("unroll") \
  for (int ni = 0; ni < 4; ++ni) { \
    acc[M0][ni] = __builtin_amdgcn_mfma_f32_16x16x32_bf16(U[0][0], bfrag[ni][0], acc[M0][ni], 0, 0, 0); \
    acc[M0][ni] = __builtin_amdgcn_mfma_f32_16x16x32_bf16(U[0][1], bfrag[ni][1], acc[M0][ni], 0, 0, 0); \
    acc[(M0) + 1][ni] = __builtin_amdgcn_mfma_f32_16x16x32_bf16(U[1][0], bfrag[ni][0], acc[(M0) + 1][ni], 0, 0, 0); \
    acc[(M0) + 1][ni] = __builtin_amdgcn_mfma_f32_16x16x32_bf16(U[1][1], bfrag[ni][1], acc[(M0) + 1][ni], 0, 0, 0); \
  } \
} while (0)

// DOST: how many halves staged this tile (literal), NVM: 6, 0, or 99(none)
#define TILE4(T, HB, DOST, NVM) do { \
  char* ldsAt_ = ldsAroot + (((T) & 1) << 16); \
  char* ldsBt_ = ldsBroot + (((T) & 1) << 16); \
  /* phase 1: read B(all) + A-q0; stage HB+0 */ \
  _Pragma("unroll") \
  for (int ni = 0; ni < 4; ++ni) { \
    bfrag[ni][0] = LDB(ldsBt_, ni, 0); bfrag[ni][1] = LDB(ldsBt_, ni, 1); } \
  aq[0][0] = LDA(ldsAt_, 0, 0); aq[0][1] = LDA(ldsAt_, 0, 1); \
  aq[1][0] = LDA(ldsAt_, 1, 0); aq[1][1] = LDA(ldsAt_, 1, 1); \
  if ((DOST) > 0) STAGE((HB) + 0); \
  BAR; PRIO1; MFMA_Q(0, aq); PRIO0; BAR; \
  /* phase 2: read A-q1 -> aq, A-q2 -> aqn; stage HB+1 */ \
  aq[0][0] = LDA(ldsAt_, 2, 0); aq[0][1] = LDA(ldsAt_, 2, 1); \
  aq[1][0] = LDA(ldsAt_, 3, 0); aq[1][1] = LDA(ldsAt_, 3, 1); \
  aqn[0][0] = LDA(ldsAt_, 4, 0); aqn[0][1] = LDA(ldsAt_, 4, 1); \
  aqn[1][0] = LDA(ldsAt_, 5, 0); aqn[1][1] = LDA(ldsAt_, 5, 1); \
  if ((DOST) > 1) STAGE((HB) + 1); \
  BAR; PRIO1; MFMA_Q(2, aq); PRIO0; BAR; \
  /* phase 3: read A-q3 -> aq; stage HB+2 */ \
  aq[0][0] = LDA(ldsAt_, 6, 0); aq[0][1] = LDA(ldsAt_, 6, 1); \
  aq[1][0] = LDA(ldsAt_, 7, 0); aq[1][1] = LDA(ldsAt_, 7, 1); \
  if ((DOST) > 2) STAGE((HB) + 2); \
  BAR; PRIO1; MFMA_Q(4, aqn); PRIO0; BAR; \
  /* phase 4: stage HB+3; vmcnt; MFMA q3 */ \
  if ((DOST) > 3) STAGE((HB) + 3); \
  if ((NVM) == 6) { VMC(6); } else if ((NVM) == 0) { VMC(0); } \
  BAR; PRIO1; MFMA_Q(6, aq); PRIO0; BAR; \
} while (0)

__global__ __launch_bounds__(512, 2) void gemm_lse_kernel(
    const unsigned short* __restrict__ xbf,   // [M_DIM][D_DIM]
    const unsigned short* __restrict__ wbf,   // [V_DIM][D_DIM]
    float* __restrict__ pMax,                 // [M_DIM][NSLOT]
    float* __restrict__ pSum) {
  __shared__ __align__(16) char lds[131072];

  const int bid0 = blockIdx.x;
  const int bid = ((bid0 & 7) << 8) | (bid0 >> 3);   // XCD swizzle (2048 % 8 == 0)
  const int vt = bid & 127, mt = bid >> 7;
  const int tid = threadIdx.x, lane = tid & 63, w = tid >> 6;
  const int wr = w >> 2, wc = w & 3;
  const int fr = lane & 15, kqg = lane >> 4;
  const int brow = (wc & 1) * 64;

  // staging addresses (issue-0 row = tid>>3; col pre-swizzled)
  const int gcol = (((tid & 7) ^ ((tid >> 3) & 7)) << 3);
  const unsigned short* aptr = xbf + (size_t)(mt * 256 + (tid >> 3)) * D_DIM + gcol;
  const unsigned short* bptr = wbf + (size_t)(vt * 256 + (tid >> 3)) * D_DIM + gcol;
  char* ldst = lds + tid * 16;

  char* ldsAroot = lds + ((2 + wr) << 14);
  char* ldsBroot = lds + ((wc >> 1) << 14);

  f32x4 acc[8][4];
#pragma unroll
  for (int i = 0; i < 8; i++)
#pragma unroll
    for (int j = 0; j < 4; j++) acc[i][j] = (f32x4){0.f, 0.f, 0.f, 0.f};

  s16x8 bfrag[4][2], aq[2][2], aqn[2][2];

  // prologue: stage halves 0..6
  STAGE(0); STAGE(1); STAGE(2); STAGE(3);
  VMC(4);
  STAGE(4); STAGE(5); STAGE(6);
  VMC(6);
  BAR;

  // main loop: 15 iterations x 2 K-tiles; epilogue tiles 30, 31
  for (int it = 0; it < 15; ++it) {
    const int t0 = it * 2, hb = it * 8 + 7;
    TILE4(t0, hb, 4, 6);
    TILE4(t0 + 1, hb + 4, 4, 6);
  }
  TILE4(30, 127, 1, 0);
  TILE4(31, 0, 0, 99);

  // epilogue: per-row (max, sumexp) over this wave's 64-col slice
  const int slot = vt * 4 + wc;
#pragma unroll
  for (int mi = 0; mi < 8; mi++) {
#pragma unroll
    for (int j = 0; j < 4; j++) {
      const int row = mt * 256 + wr * 128 + mi * 16 + kqg * 4 + j;
      float v0 = acc[mi][0][j], v1 = acc[mi][1][j];
      float v2 = acc[mi][2][j], v3 = acc[mi][3][j];
      float mx = fmaxf(fmaxf(v0, v1), fmaxf(v2, v3));
      for (int s = 1; s < 16; s <<= 1) mx = fmaxf(mx, __shfl_xor(mx, s));
      float sm = __expf(v0 - mx) + __expf(v1 - mx) +
                 __expf(v2 - mx) + __expf(v3 - mx);
      for (int s = 1; s < 16; s <<= 1) sm += __shfl_xor(sm, s);
      if (fr == 0) {
        pMax[row * NSLOT + slot] = mx;
        pSum[row * NSLOT + slot] = sm;
      }
    }
  }
}

// ---------- gather: 64 target logits + gold logit per row ----------
__global__ __launch_bounds__(256) void gather_kernel(
    const unsigned short* __restrict__ xbf,
    const unsigned short* __restrict__ wbf,
    const int* __restrict__ tgt_ids,      // [M_DIM][K_TOP]
    const int* __restrict__ true_labels,  // [M_DIM]
    float* __restrict__ gout) {           // [M_DIM][K_TOP+1]
  const int m = blockIdx.x;
  const int tid = threadIdx.x, lane = tid & 63, w = tid >> 6;
  __shared__ __align__(16) unsigned short xs[D_DIM];
  *(s16x8*)&xs[tid * 8] = *(const s16x8*)&xbf[(long long)m * D_DIM + tid * 8];
  __syncthreads();
  const int n = m & (N_SEQ - 1);
  for (int k = w; k < K_TOP + 1; k += 4) {
    int id;
    if (k < K_TOP) id = tgt_ids[m * K_TOP + k];
    else id = (n < N_SEQ - 1) ? true_labels[m + 1] : 0;
    const unsigned short* wrow = wbf + (long long)id * D_DIM;
    float accv = 0.f;
#pragma unroll
    for (int j = 0; j < 4; j++) {
      s16x8 wv = *(const s16x8*)&wrow[j * 512 + lane * 8];
      s16x8 xv = *(const s16x8*)&xs[j * 512 + lane * 8];
#pragma unroll
      for (int e = 0; e < 8; e++)
        accv += bf2f((unsigned short)wv[e]) * bf2f((unsigned short)xv[e]);
    }
    for (int s = 1; s < 64; s <<= 1) accv += __shfl_xor(accv, s);
    if (lane == 0) gout[m * (K_TOP + 1) + k] = accv;
  }
}

// ---------- final: lse merge + CE + KD, atomic into scalar ----------
__global__ __launch_bounds__(256) void reduce_kernel(
    const float* __restrict__ pMax, const float* __restrict__ pSum,
    const float* __restrict__ gout, const float* __restrict__ t_lp,
    const int* __restrict__ t_mask, float* __restrict__ out) {
  const int tid = threadIdx.x, lane = tid & 63, w = tid >> 6;
  const int m = blockIdx.x * 4 + w;

  float msl[8], ssl[8];
  float M = -1e30f;
#pragma unroll
  for (int j = 0; j < 8; j++) {
    msl[j] = pMax[m * NSLOT + lane + j * 64];
    ssl[j] = pSum[m * NSLOT + lane + j * 64];
    M = fmaxf(M, msl[j]);
  }
  for (int s = 1; s < 64; s <<= 1) M = fmaxf(M, __shfl_xor(M, s));
  float S = 0.f;
#pragma unroll
  for (int j = 0; j < 8; j++) S += ssl[j] * __expf(msl[j] - M);
  for (int s = 1; s < 64; s <<= 1) S += __shfl_xor(S, s);
  const float lse = M + logf(S);

  const int n = m & (N_SEQ - 1);
  float ce = 0.f;
  if (n < N_SEQ - 1) ce = lse - gout[m * (K_TOP + 1) + K_TOP];

  const float g = gout[m * (K_TOP + 1) + lane];
  float gM = g;
  for (int s = 1; s < 64; s <<= 1) gM = fmaxf(gM, __shfl_xor(gM, s));
  float gE = __expf(g - gM);
  float gS = gE;
  for (int s = 1; s < 64; s <<= 1) gS += __shfl_xor(gS, s);
  const float lseK = gM + logf(gS);

  const float tl = t_lp[m * K_TOP + lane];
  const int mk = t_mask[m * K_TOP + lane];
  float kd = mk ? __expf(tl) * (tl - (g - lseK)) : 0.f;
  for (int s = 1; s < 64; s <<= 1) kd += __shfl_xor(kd, s);

  if (lane == 0) atomicAdd(out, 0.5f * kd + 0.5f * ce);
}

// ---------- launch ----------
extern "C" void kernel_launch(void* const* d_in, const int* in_sizes, int n_in,
                              void* d_out, int out_size, void* d_ws, size_t ws_size,
                              hipStream_t stream) {
  const float* x   = (const float*)d_in[0];   // [2,2048,2048]
  const float* Wm  = (const float*)d_in[1];   // [32768,2048]
  const int* tids  = (const int*)d_in[2];     // [2,2048,64]
  const float* tlp = (const float*)d_in[3];   // [2,2048,64]
  const int* tmask = (const int*)d_in[4];     // [2,2048,64]
  const int* tlab  = (const int*)d_in[5];     // [2,2048]
  float* out = (float*)d_out;

  char* ws = (char*)d_ws;
  unsigned short* wbf = (unsigned short*)ws;                                 // 128 MB
  unsigned short* xbf = (unsigned short*)(ws + (size_t)V_DIM * D_DIM * 2);   // 16 MB
  float* pMax = (float*)(ws + (size_t)V_DIM * D_DIM * 2 + (size_t)M_DIM * D_DIM * 2);
  float* pSum = pMax + (size_t)M_DIM * NSLOT;
  float* gout = pSum + (size_t)M_DIM * NSLOT;

  hipMemsetAsync(d_out, 0, sizeof(float), stream);

  cast_bf16_kernel<<<8192, 256, 0, stream>>>(
      (const float4*)Wm, (uint4*)wbf, (V_DIM * D_DIM) / 8);
  cast_bf16_kernel<<<2048, 256, 0, stream>>>(
      (const float4*)x, (uint4*)xbf, (M_DIM * D_DIM) / 8);

  gemm_lse_kernel<<<(M_DIM / 256) * (V_DIM / 256), 512, 0, stream>>>(
      xbf, wbf, pMax, pSum);

  gather_kernel<<<M_DIM, 256, 0, stream>>>(xbf, wbf, tids, tlab, gout);

  reduce_kernel<<<M_DIM / 4, 256, 0, stream>>>(pMax, pSum, gout, tlp, tmask, out);
}

// Round 3
// 770.446 us; speedup vs baseline: 1.2275x; 1.0117x over previous
//
#include <hip/hip_runtime.h>
#include <hip/hip_bf16.h>
#include <stdint.h>

typedef __attribute__((ext_vector_type(8))) short s16x8;
typedef __attribute__((ext_vector_type(4))) float f32x4;

#define D_DIM 2048
#define V_DIM 32768
#define M_DIM 4096
#define N_SEQ 2048
#define K_TOP 64
#define NSLOT 512   // 128 v-tiles * 4 wc

// ---------- helpers ----------
static __device__ __forceinline__ float bf2f(unsigned short u) {
  union { unsigned int i; float f; } v; v.i = ((unsigned int)u) << 16; return v.f;
}
static __device__ __forceinline__ unsigned int pack2_bf16(float lo, float hi) {
  unsigned int ul = __float_as_uint(lo), uh = __float_as_uint(hi);
  ul = (ul + 0x7FFFu + ((ul >> 16) & 1u)) >> 16;        // RNE
  uh = (uh + 0x7FFFu + ((uh >> 16) & 1u)) >> 16;
  return ul | (uh << 16);
}
typedef __attribute__((address_space(3))) unsigned int lds_u32_t;
typedef const __attribute__((address_space(1))) unsigned int glb_u32_t;
static __device__ __forceinline__ void gload16(const void* g, void* l) {
  __builtin_amdgcn_global_load_lds((glb_u32_t*)g, (lds_u32_t*)l, 16, 0, 0);
}

// ---------- cast f32 -> bf16 ----------
__global__ void cast_bf16_kernel(const float4* __restrict__ in,
                                 uint4* __restrict__ out, int n8) {
  int i = blockIdx.x * blockDim.x + threadIdx.x;
  int stride = gridDim.x * blockDim.x;
  for (; i < n8; i += stride) {
    float4 a = in[2 * i], b = in[2 * i + 1];
    uint4 r;
    r.x = pack2_bf16(a.x, a.y);
    r.y = pack2_bf16(a.z, a.w);
    r.z = pack2_bf16(b.x, b.y);
    r.w = pack2_bf16(b.z, b.w);
    out[i] = r;
  }
}

// ---------- 256x256 8-phase pipelined GEMM + online (max,sumexp) ----------
// Tile: BM=BN=256, BK=64, 8 waves (2M x 4N), 512 thr, 128 KiB LDS dbuf.
// Half-tiles per K-tile: pos0=B[0:128), pos1=B[128:256), pos2=A[0:128), pos3=A[128:256)
// LDS swizzle: 16B-granule ^= (row & 7); inverse pre-applied on global src.
// Pipelined reads: every MFMA cluster consumes frags read >=1 barrier earlier.

#define BAR do { __builtin_amdgcn_s_barrier(); asm volatile("" ::: "memory"); } while (0)
#define VMC(N) asm volatile("s_waitcnt vmcnt(" #N ")" ::: "memory")
#define PRIO1 __builtin_amdgcn_s_setprio(1)
#define PRIO0 __builtin_amdgcn_s_setprio(0)

#define LDFRAG(BASE, R, G) \
  (*(const s16x8*)((BASE) + (R) * 128 + ((((G)) ^ ((R) & 7)) << 4)))
#define LDA(BASE, MI, KS) LDFRAG(BASE, (MI) * 16 + fr, (KS) * 4 + kqg)
#define LDB(BASE, NI, KS) LDFRAG(BASE, brow + (NI) * 16 + fr, (KS) * 4 + kqg)

#define STAGE(H) do { \
  int tt_ = (H) >> 2, pos_ = (H) & 3; \
  char* dst_ = ldst + ((tt_ & 1) << 16) + (pos_ << 14); \
  const unsigned short* src_ = ((pos_ & 2) ? aptr : bptr) \
      + ((pos_ & 1) ? (size_t)128 * D_DIM : (size_t)0) + (size_t)tt_ * 64; \
  gload16(src_, dst_); \
  gload16(src_ + (size_t)64 * D_DIM, dst_ + 8192); \
} while (0)

#define MFMA_Q(M0, U) do { \
  _Pragma("unroll") \
  for (int ni = 0; ni < 4; ++ni) { \
    acc[M0][ni] = __builtin_amdgcn_mfma_f32_16x16x32_bf16(U[0][0], bfrag[ni][0], acc[M0][ni], 0, 0, 0); \
    acc[M0][ni] = __builtin_amdgcn_mfma_f32_16x16x32_bf16(U[0][1], bfrag[ni][1], acc[M0][ni], 0, 0, 0); \
    acc[(M0) + 1][ni] = __builtin_amdgcn_mfma_f32_16x16x32_bf16(U[1][0], bfrag[ni][0], acc[(M0) + 1][ni], 0, 0, 0); \
    acc[(M0) + 1][ni] = __builtin_amdgcn_mfma_f32_16x16x32_bf16(U[1][1], bfrag[ni][1], acc[(M0) + 1][ni], 0, 0, 0); \
  } \
} while (0)

// Entering invariant: bfrag = B(T), aq = A-q0(T) (read in p4 of T-1 / prologue).
// DOST: halves staged this tile; NVM: 6, 0, or 99(none); DONEXT: read tile T+1 frags in p4.
#define TILE4(T, HB, DOST, NVM, DONEXT) do { \
  char* curA_ = ldsAroot + (((T) & 1) << 16); \
  char* nxtA_ = ldsAroot + ((((T) + 1) & 1) << 16); \
  char* nxtB_ = ldsBroot + ((((T) + 1) & 1) << 16); \
  /* p1 */ \
  if ((DOST) > 0) STAGE((HB) + 0); \
  BAR; PRIO1; MFMA_Q(0, aq); PRIO0; \
  aqn[0][0] = LDA(curA_, 2, 0); aqn[0][1] = LDA(curA_, 2, 1); \
  aqn[1][0] = LDA(curA_, 3, 0); aqn[1][1] = LDA(curA_, 3, 1); \
  BAR; \
  /* p2 */ \
  if ((DOST) > 1) STAGE((HB) + 1); \
  BAR; PRIO1; MFMA_Q(2, aqn); PRIO0; \
  aq[0][0] = LDA(curA_, 4, 0); aq[0][1] = LDA(curA_, 4, 1); \
  aq[1][0] = LDA(curA_, 5, 0); aq[1][1] = LDA(curA_, 5, 1); \
  BAR; \
  /* p3 */ \
  if ((DOST) > 2) STAGE((HB) + 2); \
  BAR; PRIO1; MFMA_Q(4, aq); PRIO0; \
  aqn[0][0] = LDA(curA_, 6, 0); aqn[0][1] = LDA(curA_, 6, 1); \
  aqn[1][0] = LDA(curA_, 7, 0); aqn[1][1] = LDA(curA_, 7, 1); \
  BAR; \
  /* p4 */ \
  if ((DOST) > 3) STAGE((HB) + 3); \
  if ((NVM) == 6) { VMC(6); } else if ((NVM) == 0) { VMC(0); } \
  BAR; PRIO1; MFMA_Q(6, aqn); PRIO0; \
  if (DONEXT) { \
    _Pragma("unroll") \
    for (int ni = 0; ni < 4; ++ni) { \
      bfrag[ni][0] = LDB(nxtB_, ni, 0); bfrag[ni][1] = LDB(nxtB_, ni, 1); } \
    aq[0][0] = LDA(nxtA_, 0, 0); aq[0][1] = LDA(nxtA_, 0, 1); \
    aq[1][0] = LDA(nxtA_, 1, 0); aq[1][1] = LDA(nxtA_, 1, 1); \
  } \
  BAR; \
} while (0)

__global__ __launch_bounds__(512, 2) void gemm_lse_kernel(
    const unsigned short* __restrict__ xbf,   // [M_DIM][D_DIM]
    const unsigned short* __restrict__ wbf,   // [V_DIM][D_DIM]
    float* __restrict__ pMax,                 // [M_DIM][NSLOT]
    float* __restrict__ pSum) {
  __shared__ __align__(16) char lds[131072];

  const int bid0 = blockIdx.x;
  const int bid = ((bid0 & 7) << 8) | (bid0 >> 3);   // XCD swizzle (2048 % 8 == 0)
  const int vt = bid & 127, mt = bid >> 7;
  const int tid = threadIdx.x, lane = tid & 63, w = tid >> 6;
  const int wr = w >> 2, wc = w & 3;
  const int fr = lane & 15, kqg = lane >> 4;
  const int brow = (wc & 1) * 64;

  // staging addresses (issue-0 row = tid>>3; col pre-swizzled)
  const int gcol = (((tid & 7) ^ ((tid >> 3) & 7)) << 3);
  const unsigned short* aptr = xbf + (size_t)(mt * 256 + (tid >> 3)) * D_DIM + gcol;
  const unsigned short* bptr = wbf + (size_t)(vt * 256 + (tid >> 3)) * D_DIM + gcol;
  char* ldst = lds + tid * 16;

  char* ldsAroot = lds + ((2 + wr) << 14);
  char* ldsBroot = lds + ((wc >> 1) << 14);

  f32x4 acc[8][4];
#pragma unroll
  for (int i = 0; i < 8; i++)
#pragma unroll
    for (int j = 0; j < 4; j++) acc[i][j] = (f32x4){0.f, 0.f, 0.f, 0.f};

  s16x8 bfrag[4][2], aq[2][2], aqn[2][2];

  // prologue: stage halves 0..6, then pre-read tile-0 B + A-q0
  STAGE(0); STAGE(1); STAGE(2); STAGE(3);
  VMC(4);
  STAGE(4); STAGE(5); STAGE(6);
  VMC(6);
  BAR;
#pragma unroll
  for (int ni = 0; ni < 4; ++ni) {
    bfrag[ni][0] = LDB(ldsBroot, ni, 0); bfrag[ni][1] = LDB(ldsBroot, ni, 1);
  }
  aq[0][0] = LDA(ldsAroot, 0, 0); aq[0][1] = LDA(ldsAroot, 0, 1);
  aq[1][0] = LDA(ldsAroot, 1, 0); aq[1][1] = LDA(ldsAroot, 1, 1);

  // main loop: 15 iterations x 2 K-tiles; tail tiles 30, 31
  for (int it = 0; it < 15; ++it) {
    const int t0 = it * 2, hb = it * 8 + 7;
    TILE4(t0, hb, 4, 6, 1);
    TILE4(t0 + 1, hb + 4, 4, 6, 1);
  }
  TILE4(30, 127, 1, 0, 1);
  TILE4(31, 0, 0, 99, 0);

  // epilogue: per-row (max, sumexp) over this wave's 64-col slice
  const int slot = vt * 4 + wc;
#pragma unroll
  for (int mi = 0; mi < 8; mi++) {
#pragma unroll
    for (int j = 0; j < 4; j++) {
      const int row = mt * 256 + wr * 128 + mi * 16 + kqg * 4 + j;
      float v0 = acc[mi][0][j], v1 = acc[mi][1][j];
      float v2 = acc[mi][2][j], v3 = acc[mi][3][j];
      float mx = fmaxf(fmaxf(v0, v1), fmaxf(v2, v3));
      for (int s = 1; s < 16; s <<= 1) mx = fmaxf(mx, __shfl_xor(mx, s));
      float sm = __expf(v0 - mx) + __expf(v1 - mx) +
                 __expf(v2 - mx) + __expf(v3 - mx);
      for (int s = 1; s < 16; s <<= 1) sm += __shfl_xor(sm, s);
      if (fr == 0) {
        pMax[row * NSLOT + slot] = mx;
        pSum[row * NSLOT + slot] = sm;
      }
    }
  }
}

// ---------- gather: 64 target logits + gold logit per row ----------
__global__ __launch_bounds__(256) void gather_kernel(
    const unsigned short* __restrict__ xbf,
    const unsigned short* __restrict__ wbf,
    const int* __restrict__ tgt_ids,      // [M_DIM][K_TOP]
    const int* __restrict__ true_labels,  // [M_DIM]
    float* __restrict__ gout) {           // [M_DIM][K_TOP+1]
  const int m = blockIdx.x;
  const int tid = threadIdx.x, lane = tid & 63, w = tid >> 6;
  __shared__ __align__(16) unsigned short xs[D_DIM];
  *(s16x8*)&xs[tid * 8] = *(const s16x8*)&xbf[(long long)m * D_DIM + tid * 8];
  __syncthreads();
  const int n = m & (N_SEQ - 1);
  for (int k = w; k < K_TOP + 1; k += 4) {
    int id;
    if (k < K_TOP) id = tgt_ids[m * K_TOP + k];
    else id = (n < N_SEQ - 1) ? true_labels[m + 1] : 0;
    const unsigned short* wrow = wbf + (long long)id * D_DIM;
    float accv = 0.f;
#pragma unroll
    for (int j = 0; j < 4; j++) {
      s16x8 wv = *(const s16x8*)&wrow[j * 512 + lane * 8];
      s16x8 xv = *(const s16x8*)&xs[j * 512 + lane * 8];
#pragma unroll
      for (int e = 0; e < 8; e++)
        accv += bf2f((unsigned short)wv[e]) * bf2f((unsigned short)xv[e]);
    }
    for (int s = 1; s < 64; s <<= 1) accv += __shfl_xor(accv, s);
    if (lane == 0) gout[m * (K_TOP + 1) + k] = accv;
  }
}

// ---------- final: lse merge + CE + KD, atomic into scalar ----------
__global__ __launch_bounds__(256) void reduce_kernel(
    const float* __restrict__ pMax, const float* __restrict__ pSum,
    const float* __restrict__ gout, const float* __restrict__ t_lp,
    const int* __restrict__ t_mask, float* __restrict__ out) {
  const int tid = threadIdx.x, lane = tid & 63, w = tid >> 6;
  const int m = blockIdx.x * 4 + w;

  float msl[8], ssl[8];
  float M = -1e30f;
#pragma unroll
  for (int j = 0; j < 8; j++) {
    msl[j] = pMax[m * NSLOT + lane + j * 64];
    ssl[j] = pSum[m * NSLOT + lane + j * 64];
    M = fmaxf(M, msl[j]);
  }
  for (int s = 1; s < 64; s <<= 1) M = fmaxf(M, __shfl_xor(M, s));
  float S = 0.f;
#pragma unroll
  for (int j = 0; j < 8; j++) S += ssl[j] * __expf(msl[j] - M);
  for (int s = 1; s < 64; s <<= 1) S += __shfl_xor(S, s);
  const float lse = M + logf(S);

  const int n = m & (N_SEQ - 1);
  float ce = 0.f;
  if (n < N_SEQ - 1) ce = lse - gout[m * (K_TOP + 1) + K_TOP];

  const float g = gout[m * (K_TOP + 1) + lane];
  float gM = g;
  for (int s = 1; s < 64; s <<= 1) gM = fmaxf(gM, __shfl_xor(gM, s));
  float gE = __expf(g - gM);
  float gS = gE;
  for (int s = 1; s < 64; s <<= 1) gS += __shfl_xor(gS, s);
  const float lseK = gM + logf(gS);

  const float tl = t_lp[m * K_TOP + lane];
  const int mk = t_mask[m * K_TOP + lane];
  float kd = mk ? __expf(tl) * (tl - (g - lseK)) : 0.f;
  for (int s = 1; s < 64; s <<= 1) kd += __shfl_xor(kd, s);

  if (lane == 0) atomicAdd(out, 0.5f * kd + 0.5f * ce);
}

// ---------- launch ----------
extern "C" void kernel_launch(void* const* d_in, const int* in_sizes, int n_in,
                              void* d_out, int out_size, void* d_ws, size_t ws_size,
                              hipStream_t stream) {
  const float* x   = (const float*)d_in[0];   // [2,2048,2048]
  const float* Wm  = (const float*)d_in[1];   // [32768,2048]
  const int* tids  = (const int*)d_in[2];     // [2,2048,64]
  const float* tlp = (const float*)d_in[3];   // [2,2048,64]
  const int* tmask = (const int*)d_in[4];     // [2,2048,64]
  const int* tlab  = (const int*)d_in[5];     // [2,2048]
  float* out = (float*)d_out;

  char* ws = (char*)d_ws;
  unsigned short* wbf = (unsigned short*)ws;                                 // 128 MB
  unsigned short* xbf = (unsigned short*)(ws + (size_t)V_DIM * D_DIM * 2);   // 16 MB
  float* pMax = (float*)(ws + (size_t)V_DIM * D_DIM * 2 + (size_t)M_DIM * D_DIM * 2);
  float* pSum = pMax + (size_t)M_DIM * NSLOT;
  float* gout = pSum + (size_t)M_DIM * NSLOT;

  hipMemsetAsync(d_out, 0, sizeof(float), stream);

  cast_bf16_kernel<<<8192, 256, 0, stream>>>(
      (const float4*)Wm, (uint4*)wbf, (V_DIM * D_DIM) / 8);
  cast_bf16_kernel<<<2048, 256, 0, stream>>>(
      (const float4*)x, (uint4*)xbf, (M_DIM * D_DIM) / 8);

  gemm_lse_kernel<<<(M_DIM / 256) * (V_DIM / 256), 512, 0, stream>>>(
      xbf, wbf, pMax, pSum);

  gather_kernel<<<M_DIM, 256, 0, stream>>>(xbf, wbf, tids, tlab, gout);

  reduce_kernel<<<M_DIM / 4, 256, 0, stream>>>(pMax, pSum, gout, tlp, tmask, out);
}

// Round 4
// 681.333 us; speedup vs baseline: 1.3881x; 1.1308x over previous
//
#include <hip/hip_runtime.h>
#include <hip/hip_bf16.h>
#include <stdint.h>

typedef __attribute__((ext_vector_type(8))) short s16x8;
typedef __attribute__((ext_vector_type(4))) float f32x4;

#define D_DIM 2048
#define V_DIM 32768
#define M_DIM 4096
#define N_SEQ 2048
#define K_TOP 64
#define NSLOT 512   // 128 v-tiles * 4 wc
#define EBCAP 512   // entries per 256x256 tile (avg ~130)

// ---------- helpers ----------
static __device__ __forceinline__ float bf2f(unsigned short u) {
  union { unsigned int i; float f; } v; v.i = ((unsigned int)u) << 16; return v.f;
}
static __device__ __forceinline__ unsigned int pack2_bf16(float lo, float hi) {
  unsigned int ul = __float_as_uint(lo), uh = __float_as_uint(hi);
  ul = (ul + 0x7FFFu + ((ul >> 16) & 1u)) >> 16;        // RNE
  uh = (uh + 0x7FFFu + ((uh >> 16) & 1u)) >> 16;
  return ul | (uh << 16);
}
typedef __attribute__((address_space(3))) unsigned int lds_u32_t;
typedef const __attribute__((address_space(1))) unsigned int glb_u32_t;
static __device__ __forceinline__ void gload16(const void* g, void* l) {
  __builtin_amdgcn_global_load_lds((glb_u32_t*)g, (lds_u32_t*)l, 16, 0, 0);
}

// ---------- cast f32 -> bf16 ----------
__global__ void cast_bf16_kernel(const float4* __restrict__ in,
                                 uint4* __restrict__ out, int n8) {
  int i = blockIdx.x * blockDim.x + threadIdx.x;
  int stride = gridDim.x * blockDim.x;
  for (; i < n8; i += stride) {
    float4 a = in[2 * i], b = in[2 * i + 1];
    uint4 r;
    r.x = pack2_bf16(a.x, a.y);
    r.y = pack2_bf16(a.z, a.w);
    r.z = pack2_bf16(b.x, b.y);
    r.w = pack2_bf16(b.z, b.w);
    out[i] = r;
  }
}

// ---------- binning: (m, id) -> per-(mt,vt)-tile entry lists ----------
__global__ __launch_bounds__(256) void bin_kernel(
    const int* __restrict__ tids, const int* __restrict__ tlab,
    unsigned int* __restrict__ cnt, unsigned int* __restrict__ ebuf) {
  int idx = blockIdx.x * 256 + threadIdx.x;
  if (idx >= M_DIM * (K_TOP + 1)) return;
  int m = idx / (K_TOP + 1), k = idx - m * (K_TOP + 1);
  int id;
  if (k < K_TOP) id = tids[m * K_TOP + k];
  else {
    int n = m & (N_SEQ - 1);
    if (n == N_SEQ - 1) return;   // no gold for last position
    id = tlab[m + 1];
  }
  int tile = ((m >> 8) << 7) + (id >> 8);   // mt*128 + vt
  unsigned int pos = atomicAdd(&cnt[tile], 1u);
  if (pos < EBCAP)
    ebuf[tile * EBCAP + pos] =
        ((unsigned int)k << 16) | ((unsigned int)(m & 255) << 8) | (unsigned int)(id & 255);
}

// ---------- 256x256 8-phase pipelined GEMM + lse partials + fused gather ----
#define BAR do { __builtin_amdgcn_s_barrier(); asm volatile("" ::: "memory"); } while (0)
#define VMC(N) asm volatile("s_waitcnt vmcnt(" #N ")" ::: "memory")
#define PRIO1 __builtin_amdgcn_s_setprio(1)
#define PRIO0 __builtin_amdgcn_s_setprio(0)

#define LDFRAG(BASE, R, G) \
  (*(const s16x8*)((BASE) + (R) * 128 + ((((G)) ^ ((R) & 7)) << 4)))
#define LDA(BASE, MI, KS) LDFRAG(BASE, (MI) * 16 + fr, (KS) * 4 + kqg)
#define LDB(BASE, NI, KS) LDFRAG(BASE, brow + (NI) * 16 + fr, (KS) * 4 + kqg)

#define STAGE(H) do { \
  int tt_ = (H) >> 2, pos_ = (H) & 3; \
  char* dst_ = ldst + ((tt_ & 1) << 16) + (pos_ << 14); \
  const unsigned short* src_ = ((pos_ & 2) ? aptr : bptr) \
      + ((pos_ & 1) ? (size_t)128 * D_DIM : (size_t)0) + (size_t)tt_ * 64; \
  gload16(src_, dst_); \
  gload16(src_ + (size_t)64 * D_DIM, dst_ + 8192); \
} while (0)

// dependent reuse distance = 8 MFMAs (k0 sweep then k1 sweep)
#define MFMA_Q(M0, U) do { \
  _Pragma("unroll") \
  for (int ni = 0; ni < 4; ++ni) \
    acc[M0][ni] = __builtin_amdgcn_mfma_f32_16x16x32_bf16(U[0][0], bfrag[ni][0], acc[M0][ni], 0, 0, 0); \
  _Pragma("unroll") \
  for (int ni = 0; ni < 4; ++ni) \
    acc[(M0) + 1][ni] = __builtin_amdgcn_mfma_f32_16x16x32_bf16(U[1][0], bfrag[ni][0], acc[(M0) + 1][ni], 0, 0, 0); \
  _Pragma("unroll") \
  for (int ni = 0; ni < 4; ++ni) \
    acc[M0][ni] = __builtin_amdgcn_mfma_f32_16x16x32_bf16(U[0][1], bfrag[ni][1], acc[M0][ni], 0, 0, 0); \
  _Pragma("unroll") \
  for (int ni = 0; ni < 4; ++ni) \
    acc[(M0) + 1][ni] = __builtin_amdgcn_mfma_f32_16x16x32_bf16(U[1][1], bfrag[ni][1], acc[(M0) + 1][ni], 0, 0, 0); \
} while (0)

// Entering invariant: bfrag = B(T), aq = A-q0(T) (read in p4 of T-1 / prologue).
#define TILE4(T, HB, DOST, NVM, DONEXT) do { \
  char* curA_ = ldsAroot + (((T) & 1) << 16); \
  char* nxtA_ = ldsAroot + ((((T) + 1) & 1) << 16); \
  char* nxtB_ = ldsBroot + ((((T) + 1) & 1) << 16); \
  /* p1 */ \
  if ((DOST) > 0) STAGE((HB) + 0); \
  BAR; PRIO1; MFMA_Q(0, aq); PRIO0; \
  aqn[0][0] = LDA(curA_, 2, 0); aqn[0][1] = LDA(curA_, 2, 1); \
  aqn[1][0] = LDA(curA_, 3, 0); aqn[1][1] = LDA(curA_, 3, 1); \
  BAR; \
  /* p2 */ \
  if ((DOST) > 1) STAGE((HB) + 1); \
  BAR; PRIO1; MFMA_Q(2, aqn); PRIO0; \
  aq[0][0] = LDA(curA_, 4, 0); aq[0][1] = LDA(curA_, 4, 1); \
  aq[1][0] = LDA(curA_, 5, 0); aq[1][1] = LDA(curA_, 5, 1); \
  BAR; \
  /* p3 */ \
  if ((DOST) > 2) STAGE((HB) + 2); \
  BAR; PRIO1; MFMA_Q(4, aq); PRIO0; \
  aqn[0][0] = LDA(curA_, 6, 0); aqn[0][1] = LDA(curA_, 6, 1); \
  aqn[1][0] = LDA(curA_, 7, 0); aqn[1][1] = LDA(curA_, 7, 1); \
  BAR; \
  /* p4 */ \
  if ((DOST) > 3) STAGE((HB) + 3); \
  if ((NVM) == 6) { VMC(6); } else if ((NVM) == 0) { VMC(0); } \
  BAR; PRIO1; MFMA_Q(6, aqn); PRIO0; \
  if (DONEXT) { \
    _Pragma("unroll") \
    for (int ni = 0; ni < 4; ++ni) { \
      bfrag[ni][0] = LDB(nxtB_, ni, 0); bfrag[ni][1] = LDB(nxtB_, ni, 1); } \
    aq[0][0] = LDA(nxtA_, 0, 0); aq[0][1] = LDA(nxtA_, 0, 1); \
    aq[1][0] = LDA(nxtA_, 1, 0); aq[1][1] = LDA(nxtA_, 1, 1); \
  } \
  BAR; \
} while (0)

__global__ __launch_bounds__(512, 2) void gemm_lse_kernel(
    const unsigned short* __restrict__ xbf,   // [M_DIM][D_DIM]
    const unsigned short* __restrict__ wbf,   // [V_DIM][D_DIM]
    float* __restrict__ pMax,                 // [M_DIM][NSLOT]
    float* __restrict__ pSum,
    const unsigned int* __restrict__ bcnt,    // [2048]
    const unsigned int* __restrict__ ebuf,    // [2048][EBCAP]
    float* __restrict__ gout) {               // [M_DIM][K_TOP+1]
  __shared__ __align__(16) char lds[131072];

  const int bid0 = blockIdx.x;
  const int bid = ((bid0 & 7) << 8) | (bid0 >> 3);   // XCD swizzle (2048 % 8 == 0)
  const int vt = bid & 127, mt = bid >> 7;
  const int tid = threadIdx.x, lane = tid & 63, w = tid >> 6;
  const int wr = w >> 2, wc = w & 3;
  const int fr = lane & 15, kqg = lane >> 4;
  const int brow = (wc & 1) * 64;

  const int gcol = (((tid & 7) ^ ((tid >> 3) & 7)) << 3);
  const unsigned short* aptr = xbf + (size_t)(mt * 256 + (tid >> 3)) * D_DIM + gcol;
  const unsigned short* bptr = wbf + (size_t)(vt * 256 + (tid >> 3)) * D_DIM + gcol;
  char* ldst = lds + tid * 16;

  char* ldsAroot = lds + ((2 + wr) << 14);
  char* ldsBroot = lds + ((wc >> 1) << 14);

  f32x4 acc[8][4];
#pragma unroll
  for (int i = 0; i < 8; i++)
#pragma unroll
    for (int j = 0; j < 4; j++) acc[i][j] = (f32x4){0.f, 0.f, 0.f, 0.f};

  s16x8 bfrag[4][2], aq[2][2], aqn[2][2];

  // prologue: stage halves 0..6, then pre-read tile-0 B + A-q0
  STAGE(0); STAGE(1); STAGE(2); STAGE(3);
  VMC(4);
  STAGE(4); STAGE(5); STAGE(6);
  VMC(6);
  BAR;
#pragma unroll
  for (int ni = 0; ni < 4; ++ni) {
    bfrag[ni][0] = LDB(ldsBroot, ni, 0); bfrag[ni][1] = LDB(ldsBroot, ni, 1);
  }
  aq[0][0] = LDA(ldsAroot, 0, 0); aq[0][1] = LDA(ldsAroot, 0, 1);
  aq[1][0] = LDA(ldsAroot, 1, 0); aq[1][1] = LDA(ldsAroot, 1, 1);

  // main loop: 15 iterations x 2 K-tiles; tail tiles 30, 31
  for (int it = 0; it < 15; ++it) {
    const int t0 = it * 2, hb = it * 8 + 7;
    TILE4(t0, hb, 4, 6, 1);
    TILE4(t0 + 1, hb + 4, 4, 6, 1);
  }
  TILE4(30, 127, 1, 0, 1);
  TILE4(31, 0, 0, 99, 0);

  // ---- epilogue A: per-row (max, sumexp) over this wave's 64-col slice ----
  const int slot = vt * 4 + wc;
#pragma unroll
  for (int mi = 0; mi < 8; mi++) {
#pragma unroll
    for (int j = 0; j < 4; j++) {
      const int row = mt * 256 + wr * 128 + mi * 16 + kqg * 4 + j;
      float v0 = acc[mi][0][j], v1 = acc[mi][1][j];
      float v2 = acc[mi][2][j], v3 = acc[mi][3][j];
      float mx = fmaxf(fmaxf(v0, v1), fmaxf(v2, v3));
      for (int s = 1; s < 16; s <<= 1) mx = fmaxf(mx, __shfl_xor(mx, s));
      float sm = __expf(v0 - mx) + __expf(v1 - mx) +
                 __expf(v2 - mx) + __expf(v3 - mx);
      for (int s = 1; s < 16; s <<= 1) sm += __shfl_xor(sm, s);
      if (fr == 0) {
        pMax[row * NSLOT + slot] = mx;
        pSum[row * NSLOT + slot] = sm;
      }
    }
  }

  // ---- epilogue B: fused gather of requested logits via LDS round-trip ----
  const int tile = (mt << 7) + vt;
  unsigned int cn = bcnt[tile];
  if (cn > EBCAP) cn = EBCAP;
  const unsigned int* elist = ebuf + tile * EBCAP;
  float* ldsf = (float*)lds;

  __syncthreads();
#pragma unroll
  for (int half = 0; half < 2; ++half) {
    if (wr == half) {
#pragma unroll
      for (int mi = 0; mi < 8; mi++)
#pragma unroll
        for (int ni = 0; ni < 4; ni++)
#pragma unroll
          for (int j = 0; j < 4; j++)
            ldsf[(mi * 16 + kqg * 4 + j) * 256 + wc * 64 + ni * 16 + fr] = acc[mi][ni][j];
    }
    __syncthreads();
    for (unsigned int e = tid; e < cn; e += 512) {
      unsigned int u = elist[e];
      int r = (u >> 8) & 255;
      if ((r >> 7) == half) {
        int c = u & 255, k = u >> 16;
        gout[(mt * 256 + r) * (K_TOP + 1) + k] = ldsf[(r & 127) * 256 + c];
      }
    }
    __syncthreads();
  }
}

// ---------- final: lse merge + CE + KD, atomic into scalar ----------
__global__ __launch_bounds__(256) void reduce_kernel(
    const float* __restrict__ pMax, const float* __restrict__ pSum,
    const float* __restrict__ gout, const float* __restrict__ t_lp,
    const int* __restrict__ t_mask, float* __restrict__ out) {
  const int tid = threadIdx.x, lane = tid & 63, w = tid >> 6;
  const int m = blockIdx.x * 4 + w;

  float msl[8], ssl[8];
  float M = -1e30f;
#pragma unroll
  for (int j = 0; j < 8; j++) {
    msl[j] = pMax[m * NSLOT + lane + j * 64];
    ssl[j] = pSum[m * NSLOT + lane + j * 64];
    M = fmaxf(M, msl[j]);
  }
  for (int s = 1; s < 64; s <<= 1) M = fmaxf(M, __shfl_xor(M, s));
  float S = 0.f;
#pragma unroll
  for (int j = 0; j < 8; j++) S += ssl[j] * __expf(msl[j] - M);
  for (int s = 1; s < 64; s <<= 1) S += __shfl_xor(S, s);
  const float lse = M + logf(S);

  const int n = m & (N_SEQ - 1);
  float ce = 0.f;
  if (n < N_SEQ - 1) ce = lse - gout[m * (K_TOP + 1) + K_TOP];

  const float g = gout[m * (K_TOP + 1) + lane];
  float gM = g;
  for (int s = 1; s < 64; s <<= 1) gM = fmaxf(gM, __shfl_xor(gM, s));
  float gE = __expf(g - gM);
  float gS = gE;
  for (int s = 1; s < 64; s <<= 1) gS += __shfl_xor(gS, s);
  const float lseK = gM + logf(gS);

  const float tl = t_lp[m * K_TOP + lane];
  const int mk = t_mask[m * K_TOP + lane];
  float kd = mk ? __expf(tl) * (tl - (g - lseK)) : 0.f;
  for (int s = 1; s < 64; s <<= 1) kd += __shfl_xor(kd, s);

  if (lane == 0) atomicAdd(out, 0.5f * kd + 0.5f * ce);
}

// ---------- launch ----------
extern "C" void kernel_launch(void* const* d_in, const int* in_sizes, int n_in,
                              void* d_out, int out_size, void* d_ws, size_t ws_size,
                              hipStream_t stream) {
  const float* x   = (const float*)d_in[0];   // [2,2048,2048]
  const float* Wm  = (const float*)d_in[1];   // [32768,2048]
  const int* tids  = (const int*)d_in[2];     // [2,2048,64]
  const float* tlp = (const float*)d_in[3];   // [2,2048,64]
  const int* tmask = (const int*)d_in[4];     // [2,2048,64]
  const int* tlab  = (const int*)d_in[5];     // [2,2048]
  float* out = (float*)d_out;

  char* ws = (char*)d_ws;
  unsigned short* wbf = (unsigned short*)ws;                                 // 128 MB
  unsigned short* xbf = (unsigned short*)(ws + (size_t)V_DIM * D_DIM * 2);   // 16 MB
  char* p = ws + (size_t)V_DIM * D_DIM * 2 + (size_t)M_DIM * D_DIM * 2;
  float* pMax = (float*)p;                       p += (size_t)M_DIM * NSLOT * 4;
  float* pSum = (float*)p;                       p += (size_t)M_DIM * NSLOT * 4;
  float* gout = (float*)p;                       p += (size_t)M_DIM * (K_TOP + 1) * 4;
  unsigned int* bcnt = (unsigned int*)p;         p += 2048 * 4;
  unsigned int* ebuf = (unsigned int*)p;         p += (size_t)2048 * EBCAP * 4;

  hipMemsetAsync(d_out, 0, sizeof(float), stream);
  hipMemsetAsync(bcnt, 0, 2048 * 4, stream);

  bin_kernel<<<(M_DIM * (K_TOP + 1) + 255) / 256, 256, 0, stream>>>(
      tids, tlab, bcnt, ebuf);

  cast_bf16_kernel<<<8192, 256, 0, stream>>>(
      (const float4*)Wm, (uint4*)wbf, (V_DIM * D_DIM) / 8);
  cast_bf16_kernel<<<2048, 256, 0, stream>>>(
      (const float4*)x, (uint4*)xbf, (M_DIM * D_DIM) / 8);

  gemm_lse_kernel<<<(M_DIM / 256) * (V_DIM / 256), 512, 0, stream>>>(
      xbf, wbf, pMax, pSum, bcnt, ebuf, gout);

  reduce_kernel<<<M_DIM / 4, 256, 0, stream>>>(pMax, pSum, gout, tlp, tmask, out);
}

// Round 5
// 669.656 us; speedup vs baseline: 1.4123x; 1.0174x over previous
//
#include <hip/hip_runtime.h>
#include <hip/hip_bf16.h>
#include <stdint.h>

typedef __attribute__((ext_vector_type(8))) short s16x8;
typedef __attribute__((ext_vector_type(4))) float f32x4;

#define D_DIM 2048
#define V_DIM 32768
#define M_DIM 4096
#define N_SEQ 2048
#define K_TOP 64
#define NSLOT 512   // 128 v-tiles * 4 wc
#define EBCAP 512   // entries per 256x256 tile (avg ~130)

// ---------- helpers ----------
static __device__ __forceinline__ float bf2f(unsigned short u) {
  union { unsigned int i; float f; } v; v.i = ((unsigned int)u) << 16; return v.f;
}
static __device__ __forceinline__ unsigned int pack2_bf16(float lo, float hi) {
  unsigned int ul = __float_as_uint(lo), uh = __float_as_uint(hi);
  ul = (ul + 0x7FFFu + ((ul >> 16) & 1u)) >> 16;        // RNE
  uh = (uh + 0x7FFFu + ((uh >> 16) & 1u)) >> 16;
  return ul | (uh << 16);
}
typedef __attribute__((address_space(3))) unsigned int lds_u32_t;
typedef const __attribute__((address_space(1))) unsigned int glb_u32_t;
static __device__ __forceinline__ void gload16(const void* g, void* l) {
  __builtin_amdgcn_global_load_lds((glb_u32_t*)g, (lds_u32_t*)l, 16, 0, 0);
}

// ---------- cast f32 -> bf16 (both tensors, one launch) ----------
__global__ void cast_bf16_kernel(const float4* __restrict__ inA, uint4* __restrict__ outA, int nA8,
                                 const float4* __restrict__ inB, uint4* __restrict__ outB, int nB8) {
  int i = blockIdx.x * blockDim.x + threadIdx.x;
  int stride = gridDim.x * blockDim.x;
  int tot = nA8 + nB8;
  for (; i < tot; i += stride) {
    const float4* in = (i < nA8) ? inA : inB;
    uint4* out = (i < nA8) ? outA : outB;
    int j = (i < nA8) ? i : i - nA8;
    float4 a = in[2 * j], b = in[2 * j + 1];
    uint4 r;
    r.x = pack2_bf16(a.x, a.y);
    r.y = pack2_bf16(a.z, a.w);
    r.z = pack2_bf16(b.x, b.y);
    r.w = pack2_bf16(b.z, b.w);
    out[j] = r;
  }
}

// ---------- binning: (m, id) -> per-(mt,vt)-tile entry lists ----------
__global__ __launch_bounds__(256) void bin_kernel(
    const int* __restrict__ tids, const int* __restrict__ tlab,
    unsigned int* __restrict__ cnt, unsigned int* __restrict__ ebuf) {
  int idx = blockIdx.x * 256 + threadIdx.x;
  if (idx >= M_DIM * (K_TOP + 1)) return;
  int m = idx / (K_TOP + 1), k = idx - m * (K_TOP + 1);
  int id;
  if (k < K_TOP) id = tids[m * K_TOP + k];
  else {
    int n = m & (N_SEQ - 1);
    if (n == N_SEQ - 1) return;   // no gold for last position
    id = tlab[m + 1];
  }
  int tile = ((m >> 8) << 7) + (id >> 8);   // mt*128 + vt
  unsigned int pos = atomicAdd(&cnt[tile], 1u);
  if (pos < EBCAP)
    ebuf[tile * EBCAP + pos] =
        ((unsigned int)k << 16) | ((unsigned int)(m & 255) << 8) | (unsigned int)(id & 255);
}

// ---------- 256x256 8-phase pipelined GEMM + lse partials + fused gather ----
#define BAR do { __builtin_amdgcn_s_barrier(); asm volatile("" ::: "memory"); } while (0)
#define VMC(N) asm volatile("s_waitcnt vmcnt(" #N ")" ::: "memory")
#define PRIO1 __builtin_amdgcn_s_setprio(1)
#define PRIO0 __builtin_amdgcn_s_setprio(0)

#define LDFRAG(BASE, R, G) \
  (*(const s16x8*)((BASE) + (R) * 128 + ((((G)) ^ ((R) & 7)) << 4)))
#define LDA(BASE, MI, KS) LDFRAG(BASE, (MI) * 16 + fr, (KS) * 4 + kqg)
#define LDB(BASE, NI, KS) LDFRAG(BASE, brow + (NI) * 16 + fr, (KS) * 4 + kqg)

#define STAGE(H) do { \
  int tt_ = (H) >> 2, pos_ = (H) & 3; \
  char* dst_ = ldst + ((tt_ & 1) << 16) + (pos_ << 14); \
  const unsigned short* src_ = ((pos_ & 2) ? aptr : bptr) \
      + ((pos_ & 1) ? (size_t)128 * D_DIM : (size_t)0) + (size_t)tt_ * 64; \
  gload16(src_, dst_); \
  gload16(src_ + (size_t)64 * D_DIM, dst_ + 8192); \
} while (0)

#define MFMA_Q(M0, U) do { \
  _Pragma("unroll") \
  for (int ni = 0; ni < 4; ++ni) \
    acc[M0][ni] = __builtin_amdgcn_mfma_f32_16x16x32_bf16(U[0][0], bfrag[ni][0], acc[M0][ni], 0, 0, 0); \
  _Pragma("unroll") \
  for (int ni = 0; ni < 4; ++ni) \
    acc[(M0) + 1][ni] = __builtin_amdgcn_mfma_f32_16x16x32_bf16(U[1][0], bfrag[ni][0], acc[(M0) + 1][ni], 0, 0, 0); \
  _Pragma("unroll") \
  for (int ni = 0; ni < 4; ++ni) \
    acc[M0][ni] = __builtin_amdgcn_mfma_f32_16x16x32_bf16(U[0][1], bfrag[ni][1], acc[M0][ni], 0, 0, 0); \
  _Pragma("unroll") \
  for (int ni = 0; ni < 4; ++ni) \
    acc[(M0) + 1][ni] = __builtin_amdgcn_mfma_f32_16x16x32_bf16(U[1][1], bfrag[ni][1], acc[(M0) + 1][ni], 0, 0, 0); \
} while (0)

// Entering invariant: bfrag = B(T), aq = A-q0(T) (read in p4 of T-1 / prologue).
#define TILE4(T, HB, DOST, NVM, DONEXT) do { \
  char* curA_ = ldsAroot + (((T) & 1) << 16); \
  char* nxtA_ = ldsAroot + ((((T) + 1) & 1) << 16); \
  char* nxtB_ = ldsBroot + ((((T) + 1) & 1) << 16); \
  /* p1 */ \
  if ((DOST) > 0) STAGE((HB) + 0); \
  BAR; PRIO1; MFMA_Q(0, aq); PRIO0; \
  aqn[0][0] = LDA(curA_, 2, 0); aqn[0][1] = LDA(curA_, 2, 1); \
  aqn[1][0] = LDA(curA_, 3, 0); aqn[1][1] = LDA(curA_, 3, 1); \
  BAR; \
  /* p2 */ \
  if ((DOST) > 1) STAGE((HB) + 1); \
  BAR; PRIO1; MFMA_Q(2, aqn); PRIO0; \
  aq[0][0] = LDA(curA_, 4, 0); aq[0][1] = LDA(curA_, 4, 1); \
  aq[1][0] = LDA(curA_, 5, 0); aq[1][1] = LDA(curA_, 5, 1); \
  BAR; \
  /* p3 */ \
  if ((DOST) > 2) STAGE((HB) + 2); \
  BAR; PRIO1; MFMA_Q(4, aq); PRIO0; \
  aqn[0][0] = LDA(curA_, 6, 0); aqn[0][1] = LDA(curA_, 6, 1); \
  aqn[1][0] = LDA(curA_, 7, 0); aqn[1][1] = LDA(curA_, 7, 1); \
  BAR; \
  /* p4 */ \
  if ((DOST) > 3) STAGE((HB) + 3); \
  if ((NVM) == 6) { VMC(6); } else if ((NVM) == 0) { VMC(0); } \
  BAR; PRIO1; MFMA_Q(6, aqn); PRIO0; \
  if (DONEXT) { \
    _Pragma("unroll") \
    for (int ni = 0; ni < 4; ++ni) { \
      bfrag[ni][0] = LDB(nxtB_, ni, 0); bfrag[ni][1] = LDB(nxtB_, ni, 1); } \
    aq[0][0] = LDA(nxtA_, 0, 0); aq[0][1] = LDA(nxtA_, 0, 1); \
    aq[1][0] = LDA(nxtA_, 1, 0); aq[1][1] = LDA(nxtA_, 1, 1); \
  } \
  BAR; \
} while (0)

__global__ __launch_bounds__(512, 2) void gemm_lse_kernel(
    const unsigned short* __restrict__ xbf,   // [M_DIM][D_DIM]
    const unsigned short* __restrict__ wbf,   // [V_DIM][D_DIM]
    float* __restrict__ pMax,                 // [M_DIM][NSLOT]
    float* __restrict__ pSum,
    const unsigned int* __restrict__ bcnt,    // [2048]
    const unsigned int* __restrict__ ebuf,    // [2048][EBCAP]
    float* __restrict__ gout) {               // [M_DIM][K_TOP+1]
  __shared__ __align__(16) char lds[131072];

  // Locality mapping: each concurrent round of 256 blocks = 16mt x 16vt square;
  // each XCD (bid0&7) pinned to 2 vt columns (2MB W slice -> L2-resident).
  const int bid0 = blockIdx.x;
  const int mt = (bid0 >> 4) & 15;
  const int vt = ((bid0 >> 8) << 4) | (bid0 & 15);
  const int tid = threadIdx.x, lane = tid & 63, w = tid >> 6;
  const int wr = w >> 2, wc = w & 3;
  const int fr = lane & 15, kqg = lane >> 4;
  const int brow = (wc & 1) * 64;

  const int gcol = (((tid & 7) ^ ((tid >> 3) & 7)) << 3);
  const unsigned short* aptr = xbf + (size_t)(mt * 256 + (tid >> 3)) * D_DIM + gcol;
  const unsigned short* bptr = wbf + (size_t)(vt * 256 + (tid >> 3)) * D_DIM + gcol;
  char* ldst = lds + tid * 16;

  char* ldsAroot = lds + ((2 + wr) << 14);
  char* ldsBroot = lds + ((wc >> 1) << 14);

  f32x4 acc[8][4];
#pragma unroll
  for (int i = 0; i < 8; i++)
#pragma unroll
    for (int j = 0; j < 4; j++) acc[i][j] = (f32x4){0.f, 0.f, 0.f, 0.f};

  s16x8 bfrag[4][2], aq[2][2], aqn[2][2];

  // prologue: stage halves 0..6, then pre-read tile-0 B + A-q0
  STAGE(0); STAGE(1); STAGE(2); STAGE(3);
  VMC(4);
  STAGE(4); STAGE(5); STAGE(6);
  VMC(6);
  BAR;
#pragma unroll
  for (int ni = 0; ni < 4; ++ni) {
    bfrag[ni][0] = LDB(ldsBroot, ni, 0); bfrag[ni][1] = LDB(ldsBroot, ni, 1);
  }
  aq[0][0] = LDA(ldsAroot, 0, 0); aq[0][1] = LDA(ldsAroot, 0, 1);
  aq[1][0] = LDA(ldsAroot, 1, 0); aq[1][1] = LDA(ldsAroot, 1, 1);

  // main loop: 15 iterations x 2 K-tiles; tail tiles 30, 31
  for (int it = 0; it < 15; ++it) {
    const int t0 = it * 2, hb = it * 8 + 7;
    TILE4(t0, hb, 4, 6, 1);
    TILE4(t0 + 1, hb + 4, 4, 6, 1);
  }
  TILE4(30, 127, 1, 0, 1);
  TILE4(31, 0, 0, 99, 0);

  // ---- epilogue A: per-row (max, sumexp) over this wave's 64-col slice ----
  const int slot = vt * 4 + wc;
#pragma unroll
  for (int mi = 0; mi < 8; mi++) {
#pragma unroll
    for (int j = 0; j < 4; j++) {
      const int row = mt * 256 + wr * 128 + mi * 16 + kqg * 4 + j;
      float v0 = acc[mi][0][j], v1 = acc[mi][1][j];
      float v2 = acc[mi][2][j], v3 = acc[mi][3][j];
      float mx = fmaxf(fmaxf(v0, v1), fmaxf(v2, v3));
      for (int s = 1; s < 16; s <<= 1) mx = fmaxf(mx, __shfl_xor(mx, s));
      float sm = __expf(v0 - mx) + __expf(v1 - mx) +
                 __expf(v2 - mx) + __expf(v3 - mx);
      for (int s = 1; s < 16; s <<= 1) sm += __shfl_xor(sm, s);
      if (fr == 0) {
        pMax[row * NSLOT + slot] = mx;
        pSum[row * NSLOT + slot] = sm;
      }
    }
  }

  // ---- epilogue B: fused gather of requested logits via LDS round-trip ----
  // col swizzle c ^= ((r>>2)&1)<<4 spreads the 4 kqg-rows across banks (2-way = free)
  const int tile = (mt << 7) + vt;
  unsigned int cn = bcnt[tile];
  if (cn > EBCAP) cn = EBCAP;
  const unsigned int* elist = ebuf + tile * EBCAP;
  float* ldsf = (float*)lds;

  __syncthreads();
#pragma unroll
  for (int half = 0; half < 2; ++half) {
    if (wr == half) {
#pragma unroll
      for (int mi = 0; mi < 8; mi++) {
        const int r0 = mi * 16 + kqg * 4;
        const int cs = (kqg & 1) << 4;
#pragma unroll
        for (int ni = 0; ni < 4; ni++) {
          const int c0 = (wc * 64 + ni * 16 + fr) ^ cs;
#pragma unroll
          for (int j = 0; j < 4; j++)
            ldsf[(r0 + j) * 256 + c0] = acc[mi][ni][j];
        }
      }
    }
    __syncthreads();
    for (unsigned int e = tid; e < cn; e += 512) {
      unsigned int u = elist[e];
      int r = (u >> 8) & 255;
      if ((r >> 7) == half) {
        int c = u & 255, k = u >> 16;
        int rl = r & 127;
        gout[(mt * 256 + r) * (K_TOP + 1) + k] = ldsf[rl * 256 + (c ^ (((rl >> 2) & 1) << 4))];
      }
    }
    __syncthreads();
  }
}

// ---------- final: lse merge + CE + KD, atomic into scalar ----------
__global__ __launch_bounds__(256) void reduce_kernel(
    const float* __restrict__ pMax, const float* __restrict__ pSum,
    const float* __restrict__ gout, const float* __restrict__ t_lp,
    const int* __restrict__ t_mask, float* __restrict__ out) {
  const int tid = threadIdx.x, lane = tid & 63, w = tid >> 6;
  const int m = blockIdx.x * 4 + w;

  float msl[8], ssl[8];
  float M = -1e30f;
#pragma unroll
  for (int j = 0; j < 8; j++) {
    msl[j] = pMax[m * NSLOT + lane + j * 64];
    ssl[j] = pSum[m * NSLOT + lane + j * 64];
    M = fmaxf(M, msl[j]);
  }
  for (int s = 1; s < 64; s <<= 1) M = fmaxf(M, __shfl_xor(M, s));
  float S = 0.f;
#pragma unroll
  for (int j = 0; j < 8; j++) S += ssl[j] * __expf(msl[j] - M);
  for (int s = 1; s < 64; s <<= 1) S += __shfl_xor(S, s);
  const float lse = M + logf(S);

  const int n = m & (N_SEQ - 1);
  float ce = 0.f;
  if (n < N_SEQ - 1) ce = lse - gout[m * (K_TOP + 1) + K_TOP];

  const float g = gout[m * (K_TOP + 1) + lane];
  float gM = g;
  for (int s = 1; s < 64; s <<= 1) gM = fmaxf(gM, __shfl_xor(gM, s));
  float gE = __expf(g - gM);
  float gS = gE;
  for (int s = 1; s < 64; s <<= 1) gS += __shfl_xor(gS, s);
  const float lseK = gM + logf(gS);

  const float tl = t_lp[m * K_TOP + lane];
  const int mk = t_mask[m * K_TOP + lane];
  float kd = mk ? __expf(tl) * (tl - (g - lseK)) : 0.f;
  for (int s = 1; s < 64; s <<= 1) kd += __shfl_xor(kd, s);

  if (lane == 0) atomicAdd(out, 0.5f * kd + 0.5f * ce);
}

// ---------- launch ----------
extern "C" void kernel_launch(void* const* d_in, const int* in_sizes, int n_in,
                              void* d_out, int out_size, void* d_ws, size_t ws_size,
                              hipStream_t stream) {
  const float* x   = (const float*)d_in[0];   // [2,2048,2048]
  const float* Wm  = (const float*)d_in[1];   // [32768,2048]
  const int* tids  = (const int*)d_in[2];     // [2,2048,64]
  const float* tlp = (const float*)d_in[3];   // [2,2048,64]
  const int* tmask = (const int*)d_in[4];     // [2,2048,64]
  const int* tlab  = (const int*)d_in[5];     // [2,2048]
  float* out = (float*)d_out;

  char* ws = (char*)d_ws;
  unsigned short* wbf = (unsigned short*)ws;                                 // 128 MB
  unsigned short* xbf = (unsigned short*)(ws + (size_t)V_DIM * D_DIM * 2);   // 16 MB
  char* p = ws + (size_t)V_DIM * D_DIM * 2 + (size_t)M_DIM * D_DIM * 2;
  float* pMax = (float*)p;                       p += (size_t)M_DIM * NSLOT * 4;
  float* pSum = (float*)p;                       p += (size_t)M_DIM * NSLOT * 4;
  float* gout = (float*)p;                       p += (size_t)M_DIM * (K_TOP + 1) * 4;
  unsigned int* bcnt = (unsigned int*)p;         p += 2048 * 4;
  unsigned int* ebuf = (unsigned int*)p;         p += (size_t)2048 * EBCAP * 4;

  hipMemsetAsync(d_out, 0, sizeof(float), stream);
  hipMemsetAsync(bcnt, 0, 2048 * 4, stream);

  bin_kernel<<<(M_DIM * (K_TOP + 1) + 255) / 256, 256, 0, stream>>>(
      tids, tlab, bcnt, ebuf);

  cast_bf16_kernel<<<8192, 256, 0, stream>>>(
      (const float4*)Wm, (uint4*)wbf, (V_DIM * D_DIM) / 8,
      (const float4*)x, (uint4*)xbf, (M_DIM * D_DIM) / 8);

  gemm_lse_kernel<<<(M_DIM / 256) * (V_DIM / 256), 512, 0, stream>>>(
      xbf, wbf, pMax, pSum, bcnt, ebuf, gout);

  reduce_kernel<<<M_DIM / 4, 256, 0, stream>>>(pMax, pSum, gout, tlp, tmask, out);
}